// Round 1
// 357.455 us; speedup vs baseline: 1.0108x; 1.0108x over previous
//
#include <hip/hip_runtime.h>

#define N_NODES 100000
#define N_EDGES 1600000
#define ET (N_EDGES + N_NODES)
#define NEG_SLOPE 0.2f

// bucket sort params
#define BSHIFT 9
#define BW 512                                  // nodes per bucket
#define NBUCK ((N_NODES + BW - 1) / BW)         // 196
#define BCAP 10240
#define BINCH 2048                              // edges per bin block

typedef unsigned short u16;
typedef unsigned int u32;

__device__ __forceinline__ float bf2f(u16 v) {
    return __uint_as_float(((u32)v) << 16);
}
__device__ __forceinline__ u16 f2bf(float f) {
    u32 u = __float_as_uint(f);
    u32 r = (u + 0x7FFFu + ((u >> 16) & 1u)) >> 16;  // RNE
    return (u16)r;
}
__device__ __forceinline__ float lrelu(float x) { return x > 0.f ? x : NEG_SLOPE * x; }
__device__ __forceinline__ float ldf(const void* p, int i, int bf) {
    return bf ? bf2f(((const u16*)p)[i]) : ((const float*)p)[i];
}
__device__ __forceinline__ int get_dst(const int* __restrict__ ei, int e, int ei64) {
    if (e < N_EDGES) return ei64 ? ei[2 * (N_EDGES + e)] : ei[N_EDGES + e];
    return e - N_EDGES;
}
__device__ __forceinline__ int get_src(const int* __restrict__ ei, int e, int ei64) {
    if (e < N_EDGES) return ei64 ? ei[2 * e] : ei[e];
    return e - N_EDGES;
}

// ---------------------------------------------------------------------------
// Detect input storage + zero bcnt (memset dispatch folded in).
// ---------------------------------------------------------------------------
__global__ void detect_kernel(const u32* __restrict__ x32, const int* __restrict__ ei,
                              int* __restrict__ flags, int* __restrict__ bcnt) {
    int lane = threadIdx.x;  // 64
    for (int i = lane; i < 256; i += 64) bcnt[i] = 0;
    u32 e = (x32[lane] >> 7) & 0xFFu;
    int ok = (e >= 96u && e <= 143u) ? 1 : 0;
    int cnt = (int)__popcll(__ballot(ok));
    int nz = (ei[2 * lane + 1] != 0) + (ei[2 * (lane + 64) + 1] != 0);
    #pragma unroll
    for (int off = 32; off > 0; off >>= 1) nz += __shfl_xor(nz, off);
    if (lane == 0) { flags[0] = (cnt >= 48) ? 1 : 0; flags[1] = (nz == 0) ? 1 : 0; }
}

// ---------------------------------------------------------------------------
// Pass 1: bin edges by dst>>9 into 196 buckets; code = (dst&511)<<17 | src.
// ---------------------------------------------------------------------------
__global__ __launch_bounds__(256) void bin_kernel(
    const int* __restrict__ ei, const int* __restrict__ flags,
    int* __restrict__ bcnt, u32* __restrict__ bbuf)
{
    __shared__ int hist[NBUCK];
    const int t = threadIdx.x;
    const int base = blockIdx.x * BINCH;
    const int ei64 = flags[1];
    for (int i = t; i < NBUCK; i += 256) hist[i] = 0;
    __syncthreads();
    for (int i = t; i < BINCH; i += 256) {
        int e = base + i;
        if (e >= ET) break;
        int d = get_dst(ei, e, ei64);
        atomicAdd(&hist[d >> BSHIFT], 1);
    }
    __syncthreads();
    for (int i = t; i < NBUCK; i += 256) {
        int c = hist[i];
        hist[i] = (c > 0) ? atomicAdd(&bcnt[i], c) : 0;
    }
    __syncthreads();
    for (int i = t; i < BINCH; i += 256) {
        int e = base + i;
        if (e >= ET) break;
        int d = get_dst(ei, e, ei64);
        int s = get_src(ei, e, ei64);
        int b = d >> BSHIFT;
        int pos = atomicAdd(&hist[b], 1);
        if (pos < BCAP)
            bbuf[(size_t)b * BCAP + pos] = ((u32)(d & (BW - 1)) << 17) | (u32)s;
    }
}

// exclusive scan of clamped bucket counts -> bbase[NBUCK+1]
__global__ __launch_bounds__(256) void bscan_kernel(
    const int* __restrict__ bcnt, int* __restrict__ bbase)
{
    __shared__ int sd[256];
    int t = threadIdx.x;
    int v = (t < NBUCK) ? min(bcnt[t], BCAP) : 0;
    sd[t] = v;
    __syncthreads();
    for (int off = 1; off < 256; off <<= 1) {
        int x = (t >= off) ? sd[t - off] : 0;
        __syncthreads();
        sd[t] += x;
        __syncthreads();
    }
    if (t < NBUCK) bbase[t] = sd[t] - v;
    if (t == NBUCK - 1) bbase[NBUCK] = sd[t];
}

// ---------------------------------------------------------------------------
// Pass 2: one block (1024 threads) per bucket -> rowptr + dst-sorted ssrc.
// ---------------------------------------------------------------------------
__global__ __launch_bounds__(1024) void scatter_kernel(
    const int* __restrict__ bcnt, const int* __restrict__ bbase,
    const u32* __restrict__ bbuf, int* __restrict__ rowptr, int* __restrict__ ssrc)
{
    __shared__ int hist[BW];
    __shared__ int cur[BW];
    __shared__ int wtot[4];
    __shared__ int lds_s[BCAP];
    const int t = threadIdx.x;
    const int b = blockIdx.x;
    const int cnt = min(bcnt[b], BCAP);
    const int base = bbase[b];
    const u32* mybuf = bbuf + (size_t)b * BCAP;

    if (t < BW) hist[t] = 0;
    __syncthreads();
    for (int i = t; i < cnt; i += 1024) atomicAdd(&hist[(int)(mybuf[i] >> 17)], 1);
    __syncthreads();
    int a0 = 0, a1 = 0, s = 0, v = 0;
    const int lane = t & 63, wid = t >> 6;
    if (t < 256) {
        a0 = hist[2 * t]; a1 = hist[2 * t + 1];
        s = a0 + a1;
        v = s;
        #pragma unroll
        for (int off = 1; off < 64; off <<= 1) {
            int n = __shfl_up(v, off);
            if (lane >= off) v += n;
        }
        if (lane == 63) wtot[wid] = v;
    }
    __syncthreads();
    if (t == 0) {
        int acc = 0;
        #pragma unroll
        for (int w = 0; w < 4; ++w) { int tmp = wtot[w]; wtot[w] = acc; acc += tmp; }
    }
    __syncthreads();
    if (t < 256) {
        int excl = v + wtot[wid] - s;
        cur[2 * t] = excl;
        cur[2 * t + 1] = excl + a0;
    }
    __syncthreads();
    if (t < BW) {
        int g = b * BW + t;
        if (g < N_NODES) rowptr[g] = base + cur[t];
    }
    if (b == NBUCK - 1 && t == 0) rowptr[N_NODES] = bbase[NBUCK];
    __syncthreads();
    for (int i = t; i < cnt; i += 1024) {
        u32 code = mybuf[i];
        int pos = atomicAdd(&cur[(int)(code >> 17)], 1);
        lds_s[pos] = (int)(code & 0x1FFFFu);
    }
    __syncthreads();
    for (int i = t; i < cnt; i += 1024) ssrc[base + i] = lds_s[i];
}

// ---------------------------------------------------------------------------
// GEMM1: h[N,64](bf16) = x[N,128] @ W[128,64]; as_/ad_ score dots.
// ---------------------------------------------------------------------------
__global__ __launch_bounds__(256) void gemm1_kernel(
    const float* __restrict__ x, const float* __restrict__ W,
    const void* __restrict__ a_src, const void* __restrict__ a_dst,
    const int* __restrict__ flags,
    u16* __restrict__ h, float* __restrict__ as_, float* __restrict__ ad_)
{
    __shared__ float xs[256 * 33];   // 33.8 KB
    __shared__ float Wl[32 * 64];    // 8 KB
    const int t = threadIdx.x;
    const int node0 = blockIdx.x * 256;
    const int bf = flags[0];
    const int ng = t >> 3;
    const int cg = t & 7;

    float acc[8][8];
    #pragma unroll
    for (int i = 0; i < 8; ++i)
        #pragma unroll
        for (int j = 0; j < 8; ++j) acc[i][j] = 0.f;

    for (int kc = 0; kc < 4; ++kc) {
        const int kb = kc * 32;
        const int c4 = t & 7;
        #pragma unroll
        for (int p = 0; p < 8; ++p) {
            int row = (t >> 3) + p * 32;
            int n = node0 + row;
            float4 vv = make_float4(0.f, 0.f, 0.f, 0.f);
            if (n < N_NODES) {
                if (!bf) {
                    vv = *(const float4*)(x + (size_t)n * 128 + kb + c4 * 4);
                } else {
                    const u16* xh = (const u16*)x;
                    vv.x = bf2f(xh[(size_t)n * 128 + kb + c4 * 4 + 0]);
                    vv.y = bf2f(xh[(size_t)n * 128 + kb + c4 * 4 + 1]);
                    vv.z = bf2f(xh[(size_t)n * 128 + kb + c4 * 4 + 2]);
                    vv.w = bf2f(xh[(size_t)n * 128 + kb + c4 * 4 + 3]);
                }
            }
            float* dstp = &xs[row * 33 + c4 * 4];
            dstp[0] = vv.x; dstp[1] = vv.y; dstp[2] = vv.z; dstp[3] = vv.w;
        }
        if (!bf) {
            #pragma unroll
            for (int qq = 0; qq < 2; ++qq) {
                int f4 = t * 2 + qq;
                ((float4*)Wl)[f4] = ((const float4*)(W + (size_t)kb * 64))[f4];
            }
        } else {
            const u16* Wh = (const u16*)W;
            for (int i = t; i < 2048; i += 256) Wl[i] = bf2f(Wh[(size_t)kb * 64 + i]);
        }
        __syncthreads();

        for (int kk = 0; kk < 32; ++kk) {
            float xr[8];
            #pragma unroll
            for (int i = 0; i < 8; ++i) xr[i] = xs[(ng * 8 + i) * 33 + kk];
            float4 w0 = *(const float4*)&Wl[kk * 64 + cg * 8];
            float4 w1 = *(const float4*)&Wl[kk * 64 + cg * 8 + 4];
            const float wr[8] = {w0.x, w0.y, w0.z, w0.w, w1.x, w1.y, w1.z, w1.w};
            #pragma unroll
            for (int i = 0; i < 8; ++i)
                #pragma unroll
                for (int j = 0; j < 8; ++j)
                    acc[i][j] = fmaf(xr[i], wr[j], acc[i][j]);
        }
        __syncthreads();
    }

    float av[8], dv[8];
    #pragma unroll
    for (int j = 0; j < 8; ++j) {
        av[j] = ldf(a_src, cg * 8 + j, bf);
        dv[j] = ldf(a_dst, cg * 8 + j, bf);
    }
    #pragma unroll
    for (int i = 0; i < 8; ++i) {
        int n = node0 + ng * 8 + i;
        float ps = 0.f, pd = 0.f;
        #pragma unroll
        for (int j = 0; j < 8; ++j) { ps += acc[i][j] * av[j]; pd += acc[i][j] * dv[j]; }
        #pragma unroll
        for (int off = 1; off < 8; off <<= 1) {
            ps += __shfl_xor(ps, off);
            pd += __shfl_xor(pd, off);
        }
        if (n < N_NODES) {
            uint4 hv;
            hv.x = (u32)f2bf(acc[i][0]) | ((u32)f2bf(acc[i][1]) << 16);
            hv.y = (u32)f2bf(acc[i][2]) | ((u32)f2bf(acc[i][3]) << 16);
            hv.z = (u32)f2bf(acc[i][4]) | ((u32)f2bf(acc[i][5]) << 16);
            hv.w = (u32)f2bf(acc[i][6]) | ((u32)f2bf(acc[i][7]) << 16);
            *(uint4*)&h[(size_t)n * 64 + cg * 8] = hv;
            if (cg == 0) { as_[n] = ps; ad_[n] = pd; }
        }
    }
}

// ---------------------------------------------------------------------------
// Layer-1 aggregation, C=64. One wave per dst. Half-split u32 gather: 2 edges
// per load instruction. (w,s) broadcast via wave-private LDS pair table:
// one ds_read_b64 per group on the idle DS pipe replaces the readlane+cndmask
// VALU chain (kernel was VALU-issue-bound: VALUBusy 83%, HBM 15%).
// sj is pre-scaled to a row byte offset so gather address is a single v_add.
// ---------------------------------------------------------------------------
__global__ __launch_bounds__(256) void gat_agg64_kernel(
    const int* __restrict__ rowptr, const int* __restrict__ ssrc,
    const float* __restrict__ as_, const float* __restrict__ ad_,
    const u16* __restrict__ h, float* __restrict__ agg)
{
    __shared__ uint2 pr[4][64];      // per-wave {ex_bits, sj<<7} pair table
    const int lane = threadIdx.x & 63;
    const int wid = threadIdx.x >> 6;
    const int dst = blockIdx.x * 4 + wid;
    if (dst >= N_NODES) return;
    uint2* pairs = pr[wid];
    const int beg = rowptr[dst], end = rowptr[dst + 1];
    const float add = ad_[dst];
    const int half = lane >> 5;
    const int hw = lane & 31;                     // u32 index within 128-B row
    const char* __restrict__ hb = (const char*)h; // byte base of h
    const u32 boff = (u32)(hw * 4);

    float m = -1e30f, l = 0.f, acc0 = 0.f, acc1 = 0.f;
    for (int base = beg; base < end; base += 64) {
        int j = base + lane;
        int sj = 0;
        float sc = -1e30f;
        if (j < end) { sj = ssrc[j]; sc = lrelu(as_[sj] + add); }
        float cm = sc;
        #pragma unroll
        for (int off = 32; off > 0; off >>= 1) cm = fmaxf(cm, __shfl_xor(cm, off));
        float nm = fmaxf(m, cm);
        float scale = __expf(m - nm);
        float ex = (j < end) ? __expf(sc - nm) : 0.f;
        float cs = ex;
        #pragma unroll
        for (int off = 32; off > 0; off >>= 1) cs += __shfl_xor(cs, off);
        l = l * scale + cs;
        acc0 *= scale; acc1 *= scale;
        m = nm;

        // publish {weight, row byte-offset} for this 64-edge block
        pairs[lane] = make_uint2(__float_as_uint(ex), ((u32)sj) << 7);
        __builtin_amdgcn_wave_barrier();
        asm volatile("s_waitcnt lgkmcnt(0)" ::: "memory");

        const int cnt = min(64, end - base);
        int jj = 0;
        for (; jj + 8 <= cnt; jj += 8) {
            #pragma unroll
            for (int k = 0; k < 8; k += 2) {
                uint2 p = pairs[jj + k + half];
                float w = __uint_as_float(p.x);
                u32 qv = *(const u32*)(hb + (size_t)(p.y + boff));
                acc0 = fmaf(w, __uint_as_float(qv << 16), acc0);
                acc1 = fmaf(w, __uint_as_float(qv & 0xFFFF0000u), acc1);
            }
        }
        for (; jj + 2 <= cnt; jj += 2) {
            uint2 p = pairs[jj + half];
            float w = __uint_as_float(p.x);
            u32 qv = *(const u32*)(hb + (size_t)(p.y + boff));
            acc0 = fmaf(w, __uint_as_float(qv << 16), acc0);
            acc1 = fmaf(w, __uint_as_float(qv & 0xFFFF0000u), acc1);
        }
        if (jj < cnt) {   // odd leftover: only half==0 contributes
            uint2 p = pairs[jj];
            float w = half ? 0.f : __uint_as_float(p.x);
            u32 qv = *(const u32*)(hb + (size_t)(p.y + boff));
            acc0 = fmaf(w, __uint_as_float(qv << 16), acc0);
            acc1 = fmaf(w, __uint_as_float(qv & 0xFFFF0000u), acc1);
        }
        __builtin_amdgcn_wave_barrier();   // keep reads before next block's write
    }
    acc0 += __shfl_xor(acc0, 32);
    acc1 += __shfl_xor(acc1, 32);
    if (lane < 32) {
        float inv = 1.f / l;
        *(float2*)&agg[(size_t)dst * 64 + 2 * hw] = make_float2(acc0 * inv, acc1 * inv);
    }
}

// ---------------------------------------------------------------------------
// Layer-2 aggregation, C=32, quarter-split u32 gather (4 edges per load
// instruction) with LDS pair-table broadcast; fused bias + log_softmax.
// Masked tail retires up to 3 leftover edges in a single pass.
// ---------------------------------------------------------------------------
__global__ __launch_bounds__(256) void gat_agg32_lsm_kernel(
    const int* __restrict__ rowptr, const int* __restrict__ ssrc,
    const float* __restrict__ as_, const float* __restrict__ ad_,
    const u16* __restrict__ h, const void* __restrict__ b2,
    const int* __restrict__ flags, float* __restrict__ out)
{
    __shared__ uint2 pr[4][64];      // per-wave {ex_bits, sj<<6} pair table
    const int lane = threadIdx.x & 63;
    const int wid = threadIdx.x >> 6;
    const int dst = blockIdx.x * 4 + wid;
    if (dst >= N_NODES) return;
    uint2* pairs = pr[wid];
    const int beg = rowptr[dst], end = rowptr[dst + 1];
    const float add = ad_[dst];
    const int q = lane >> 4;          // quarter 0..3 (edge within group of 4)
    const int i16 = lane & 15;        // u32 index within 64-B row
    const int bf = flags[0];
    const char* __restrict__ hb = (const char*)h;
    const u32 boff = (u32)(i16 * 4);

    float m = -1e30f, l = 0.f, acc0 = 0.f, acc1 = 0.f;
    for (int base = beg; base < end; base += 64) {
        int j = base + lane;
        int sj = 0;
        float sc = -1e30f;
        if (j < end) { sj = ssrc[j]; sc = lrelu(as_[sj] + add); }
        float cm = sc;
        #pragma unroll
        for (int off = 32; off > 0; off >>= 1) cm = fmaxf(cm, __shfl_xor(cm, off));
        float nm = fmaxf(m, cm);
        float scale = __expf(m - nm);
        float ex = (j < end) ? __expf(sc - nm) : 0.f;
        float cs = ex;
        #pragma unroll
        for (int off = 32; off > 0; off >>= 1) cs += __shfl_xor(cs, off);
        l = l * scale + cs;
        acc0 *= scale; acc1 *= scale;
        m = nm;

        pairs[lane] = make_uint2(__float_as_uint(ex), ((u32)sj) << 6);
        __builtin_amdgcn_wave_barrier();
        asm volatile("s_waitcnt lgkmcnt(0)" ::: "memory");

        const int cnt = min(64, end - base);
        int jj = 0;
        for (; jj + 8 <= cnt; jj += 8) {
            #pragma unroll
            for (int k = 0; k < 8; k += 4) {
                uint2 p = pairs[jj + k + q];
                float w = __uint_as_float(p.x);
                u32 qv = *(const u32*)(hb + (size_t)(p.y + boff));
                acc0 = fmaf(w, __uint_as_float(qv << 16), acc0);
                acc1 = fmaf(w, __uint_as_float(qv & 0xFFFF0000u), acc1);
            }
        }
        for (; jj + 4 <= cnt; jj += 4) {
            uint2 p = pairs[jj + q];
            float w = __uint_as_float(p.x);
            u32 qv = *(const u32*)(hb + (size_t)(p.y + boff));
            acc0 = fmaf(w, __uint_as_float(qv << 16), acc0);
            acc1 = fmaf(w, __uint_as_float(qv & 0xFFFF0000u), acc1);
        }
        {   // masked tail: up to 3 leftover edges in one pass (quarter q takes jj+q)
            int rem = cnt - jj;
            if (rem > 0) {
                uint2 p = pairs[jj + min(q, rem - 1)];
                float w = (q < rem) ? __uint_as_float(p.x) : 0.f;
                u32 qv = *(const u32*)(hb + (size_t)(p.y + boff));
                acc0 = fmaf(w, __uint_as_float(qv << 16), acc0);
                acc1 = fmaf(w, __uint_as_float(qv & 0xFFFF0000u), acc1);
            }
        }
        __builtin_amdgcn_wave_barrier();   // keep reads before next block's write
    }
    acc0 += __shfl_xor(acc0, 16); acc0 += __shfl_xor(acc0, 32);
    acc1 += __shfl_xor(acc1, 16); acc1 += __shfl_xor(acc1, 32);

    // fused bias + log_softmax: 16 lanes x 2 channels (replicated across quarters)
    float inv = 1.f / l;
    float v0 = acc0 * inv + ldf(b2, 2 * i16, bf);
    float v1 = acc1 * inv + ldf(b2, 2 * i16 + 1, bf);
    float mx = fmaxf(v0, v1);
    #pragma unroll
    for (int off = 1; off < 16; off <<= 1) mx = fmaxf(mx, __shfl_xor(mx, off));
    float ss = __expf(v0 - mx) + __expf(v1 - mx);
    #pragma unroll
    for (int off = 1; off < 16; off <<= 1) ss += __shfl_xor(ss, off);
    float lg = mx + __logf(ss);
    if (lane < 16)
        *(float2*)&out[(size_t)dst * 32 + 2 * i16] = make_float2(v0 - lg, v1 - lg);
}

// ---------------------------------------------------------------------------
// GEMM2: hin = relu(agg1 + b1); h2[N,32](bf16) = hin[N,64] @ W[64,32]; alphas.
// ---------------------------------------------------------------------------
__global__ __launch_bounds__(256) void gemm2_kernel(
    const float* __restrict__ agg1, const void* __restrict__ b1,
    const u32* __restrict__ W32, const void* __restrict__ a_src,
    const void* __restrict__ a_dst, const int* __restrict__ flags,
    u16* __restrict__ h, float* __restrict__ as_, float* __restrict__ ad_)
{
    __shared__ __align__(16) float Wl[64 * 32];
    __shared__ __align__(16) float xs[64 * 68];
    const int tid = threadIdx.x;
    const int node0 = blockIdx.x * 64;
    const int bf = flags[0];

    if (bf) {
        for (int i = tid; i < 1024; i += 256) {
            u32 u = W32[i];
            *(float2*)&Wl[2 * i] = make_float2(__uint_as_float(u << 16),
                                               __uint_as_float(u & 0xFFFF0000u));
        }
    } else {
        for (int i = tid; i < 2048; i += 256) Wl[i] = __uint_as_float(W32[i]);
    }
    for (int i = tid; i < 64 * 64; i += 256) {
        int nl = i >> 6, k = i & 63;
        int n = node0 + nl;
        float v = 0.f;
        if (n < N_NODES) v = agg1[(size_t)n * 64 + k] + ldf(b1, k, bf);
        xs[nl * 68 + k] = fmaxf(v, 0.f);
    }
    __syncthreads();

    const int ch0 = (tid & 7) * 4;
    const int n0 = (tid >> 3) * 2;
    float acc0[4] = {0.f, 0.f, 0.f, 0.f}, acc1[4] = {0.f, 0.f, 0.f, 0.f};
    for (int k = 0; k < 64; k += 4) {
        float4 xa = *(const float4*)&xs[n0 * 68 + k];
        float4 xb = *(const float4*)&xs[(n0 + 1) * 68 + k];
        const float* xap = (const float*)&xa;
        const float* xbp = (const float*)&xb;
        #pragma unroll
        for (int kk = 0; kk < 4; ++kk) {
            float4 w = *(const float4*)&Wl[(k + kk) * 32 + ch0];
            float va = xap[kk], vb = xbp[kk];
            acc0[0] += va * w.x; acc0[1] += va * w.y; acc0[2] += va * w.z; acc0[3] += va * w.w;
            acc1[0] += vb * w.x; acc1[1] += vb * w.y; acc1[2] += vb * w.z; acc1[3] += vb * w.w;
        }
    }
    float ps0 = 0.f, ps1 = 0.f, pd0 = 0.f, pd1 = 0.f;
    #pragma unroll
    for (int q = 0; q < 4; ++q) {
        float asv = ldf(a_src, ch0 + q, bf);
        float adv = ldf(a_dst, ch0 + q, bf);
        ps0 += acc0[q] * asv; pd0 += acc0[q] * adv;
        ps1 += acc1[q] * asv; pd1 += acc1[q] * adv;
    }
    #pragma unroll
    for (int off = 1; off < 8; off <<= 1) {
        ps0 += __shfl_xor(ps0, off);
        pd0 += __shfl_xor(pd0, off);
        ps1 += __shfl_xor(ps1, off);
        pd1 += __shfl_xor(pd1, off);
    }
    int na = node0 + n0, nb = na + 1;
    if (na < N_NODES) {
        u32 p0 = (u32)f2bf(acc0[0]) | ((u32)f2bf(acc0[1]) << 16);
        u32 p1 = (u32)f2bf(acc0[2]) | ((u32)f2bf(acc0[3]) << 16);
        *(uint2*)&h[(size_t)na * 32 + ch0] = make_uint2(p0, p1);
        if ((tid & 7) == 0) { as_[na] = ps0; ad_[na] = pd0; }
    }
    if (nb < N_NODES) {
        u32 p0 = (u32)f2bf(acc1[0]) | ((u32)f2bf(acc1[1]) << 16);
        u32 p1 = (u32)f2bf(acc1[2]) | ((u32)f2bf(acc1[3]) << 16);
        *(uint2*)&h[(size_t)nb * 32 + ch0] = make_uint2(p0, p1);
        if ((tid & 7) == 0) { as_[nb] = ps1; ad_[nb] = pd1; }
    }
}

// ---------------------------------------------------------------------------
extern "C" void kernel_launch(void* const* d_in, const int* in_sizes, int n_in,
                              void* d_out, int out_size, void* d_ws, size_t ws_size,
                              hipStream_t stream) {
    const float* x   = (const float*)d_in[0];
    const int* ei    = (const int*)d_in[1];
    const float* W1  = (const float*)d_in[2];
    const void* a_s1 = d_in[3];
    const void* a_d1 = d_in[4];
    const void* b1   = d_in[5];
    const u32* W2    = (const u32*)d_in[6];
    const void* a_s2 = d_in[7];
    const void* a_d2 = d_in[8];
    const void* b2   = d_in[9];
    float* out = (float*)d_out;

    // workspace carve-up (~55 MB)
    char* base = (char*)d_ws;
    int* flags = (int*)base;
    u16* h     = (u16*)(base + 64);                           // N*64 bf16 (reused N*32)
    char* q = base + 64 + (size_t)N_NODES * 64 * 2;
    float* as1 = (float*)q; q += (size_t)N_NODES * 4;
    float* ad1 = (float*)q; q += (size_t)N_NODES * 4;
    float* as2 = (float*)q; q += (size_t)N_NODES * 4;
    float* ad2 = (float*)q; q += (size_t)N_NODES * 4;
    float* agg1 = (float*)q; q += (size_t)N_NODES * 64 * 4;
    u32*  bbuf  = (u32*)q;  q += (size_t)NBUCK * BCAP * 4;    // 8.03 MB
    int* rowptr = (int*)q;  q += (size_t)(N_NODES + 16) * 4;
    int* ssrc   = (int*)q;  q += (size_t)ET * 4;
    int* bcnt   = (int*)q;  q += 256 * 4;
    int* bbase  = (int*)q;  q += 256 * 4;

    detect_kernel<<<1, 64, 0, stream>>>((const u32*)x, ei, flags, bcnt);

    // CSR by dst via 2-pass bucket sort (rowptr built in scatter)
    bin_kernel<<<(ET + BINCH - 1) / BINCH, 256, 0, stream>>>(ei, flags, bcnt, bbuf);
    bscan_kernel<<<1, 256, 0, stream>>>(bcnt, bbase);
    scatter_kernel<<<NBUCK, 1024, 0, stream>>>(bcnt, bbase, bbuf, rowptr, ssrc);

    // layer 1
    gemm1_kernel<<<(N_NODES + 255) / 256, 256, 0, stream>>>(x, W1, a_s1, a_d1, flags, h, as1, ad1);
    gat_agg64_kernel<<<(N_NODES + 3) / 4, 256, 0, stream>>>(rowptr, ssrc, as1, ad1, h, agg1);

    // layer 2 (lsm fused; writes d_out directly)
    gemm2_kernel<<<(N_NODES + 63) / 64, 256, 0, stream>>>(agg1, b1, W2, a_s2, a_d2, flags, h, as2, ad2);
    gat_agg32_lsm_kernel<<<(N_NODES + 3) / 4, 256, 0, stream>>>(rowptr, ssrc, as2, ad2, h, b2, flags, out);
}

// Round 2
// 318.061 us; speedup vs baseline: 1.1360x; 1.1239x over previous
//
#include <hip/hip_runtime.h>

#define N_NODES 100000
#define N_EDGES 1600000
#define ET (N_EDGES + N_NODES)
#define NEG_SLOPE 0.2f

// bucket sort params
#define BSHIFT 9
#define BW 512                                  // nodes per bucket
#define NBUCK ((N_NODES + BW - 1) / BW)         // 196
#define BCAP 10240
#define BINCH 2048                              // edges per bin block

typedef unsigned short u16;
typedef unsigned int u32;

__device__ __forceinline__ float bf2f(u16 v) {
    return __uint_as_float(((u32)v) << 16);
}
__device__ __forceinline__ u16 f2bf(float f) {
    u32 u = __float_as_uint(f);
    u32 r = (u + 0x7FFFu + ((u >> 16) & 1u)) >> 16;  // RNE
    return (u16)r;
}
__device__ __forceinline__ float lrelu(float x) { return x > 0.f ? x : NEG_SLOPE * x; }
__device__ __forceinline__ float ldf(const void* p, int i, int bf) {
    return bf ? bf2f(((const u16*)p)[i]) : ((const float*)p)[i];
}
__device__ __forceinline__ int get_dst(const int* __restrict__ ei, int e, int ei64) {
    if (e < N_EDGES) return ei64 ? ei[2 * (N_EDGES + e)] : ei[N_EDGES + e];
    return e - N_EDGES;
}
__device__ __forceinline__ int get_src(const int* __restrict__ ei, int e, int ei64) {
    if (e < N_EDGES) return ei64 ? ei[2 * e] : ei[e];
    return e - N_EDGES;
}

// ---------------------------------------------------------------------------
// Detect input storage + zero bcnt (memset dispatch folded in).
// ---------------------------------------------------------------------------
__global__ void detect_kernel(const u32* __restrict__ x32, const int* __restrict__ ei,
                              int* __restrict__ flags, int* __restrict__ bcnt) {
    int lane = threadIdx.x;  // 64
    for (int i = lane; i < 256; i += 64) bcnt[i] = 0;
    u32 e = (x32[lane] >> 7) & 0xFFu;
    int ok = (e >= 96u && e <= 143u) ? 1 : 0;
    int cnt = (int)__popcll(__ballot(ok));
    int nz = (ei[2 * lane + 1] != 0) + (ei[2 * (lane + 64) + 1] != 0);
    #pragma unroll
    for (int off = 32; off > 0; off >>= 1) nz += __shfl_xor(nz, off);
    if (lane == 0) { flags[0] = (cnt >= 48) ? 1 : 0; flags[1] = (nz == 0) ? 1 : 0; }
}

// ---------------------------------------------------------------------------
// Pass 1: bin edges by dst>>9 into 196 buckets; code = (dst&511)<<17 | src.
// ---------------------------------------------------------------------------
__global__ __launch_bounds__(256) void bin_kernel(
    const int* __restrict__ ei, const int* __restrict__ flags,
    int* __restrict__ bcnt, u32* __restrict__ bbuf)
{
    __shared__ int hist[NBUCK];
    const int t = threadIdx.x;
    const int base = blockIdx.x * BINCH;
    const int ei64 = flags[1];
    for (int i = t; i < NBUCK; i += 256) hist[i] = 0;
    __syncthreads();
    for (int i = t; i < BINCH; i += 256) {
        int e = base + i;
        if (e >= ET) break;
        int d = get_dst(ei, e, ei64);
        atomicAdd(&hist[d >> BSHIFT], 1);
    }
    __syncthreads();
    for (int i = t; i < NBUCK; i += 256) {
        int c = hist[i];
        hist[i] = (c > 0) ? atomicAdd(&bcnt[i], c) : 0;
    }
    __syncthreads();
    for (int i = t; i < BINCH; i += 256) {
        int e = base + i;
        if (e >= ET) break;
        int d = get_dst(ei, e, ei64);
        int s = get_src(ei, e, ei64);
        int b = d >> BSHIFT;
        int pos = atomicAdd(&hist[b], 1);
        if (pos < BCAP)
            bbuf[(size_t)b * BCAP + pos] = ((u32)(d & (BW - 1)) << 17) | (u32)s;
    }
}

// exclusive scan of clamped bucket counts -> bbase[NBUCK+1]
__global__ __launch_bounds__(256) void bscan_kernel(
    const int* __restrict__ bcnt, int* __restrict__ bbase)
{
    __shared__ int sd[256];
    int t = threadIdx.x;
    int v = (t < NBUCK) ? min(bcnt[t], BCAP) : 0;
    sd[t] = v;
    __syncthreads();
    for (int off = 1; off < 256; off <<= 1) {
        int x = (t >= off) ? sd[t - off] : 0;
        __syncthreads();
        sd[t] += x;
        __syncthreads();
    }
    if (t < NBUCK) bbase[t] = sd[t] - v;
    if (t == NBUCK - 1) bbase[NBUCK] = sd[t];
}

// ---------------------------------------------------------------------------
// Pass 2: one block (1024 threads) per bucket -> rowptr + dst-sorted ssrc.
// ---------------------------------------------------------------------------
__global__ __launch_bounds__(1024) void scatter_kernel(
    const int* __restrict__ bcnt, const int* __restrict__ bbase,
    const u32* __restrict__ bbuf, int* __restrict__ rowptr, int* __restrict__ ssrc)
{
    __shared__ int hist[BW];
    __shared__ int cur[BW];
    __shared__ int wtot[4];
    __shared__ int lds_s[BCAP];
    const int t = threadIdx.x;
    const int b = blockIdx.x;
    const int cnt = min(bcnt[b], BCAP);
    const int base = bbase[b];
    const u32* mybuf = bbuf + (size_t)b * BCAP;

    if (t < BW) hist[t] = 0;
    __syncthreads();
    for (int i = t; i < cnt; i += 1024) atomicAdd(&hist[(int)(mybuf[i] >> 17)], 1);
    __syncthreads();
    int a0 = 0, a1 = 0, s = 0, v = 0;
    const int lane = t & 63, wid = t >> 6;
    if (t < 256) {
        a0 = hist[2 * t]; a1 = hist[2 * t + 1];
        s = a0 + a1;
        v = s;
        #pragma unroll
        for (int off = 1; off < 64; off <<= 1) {
            int n = __shfl_up(v, off);
            if (lane >= off) v += n;
        }
        if (lane == 63) wtot[wid] = v;
    }
    __syncthreads();
    if (t == 0) {
        int acc = 0;
        #pragma unroll
        for (int w = 0; w < 4; ++w) { int tmp = wtot[w]; wtot[w] = acc; acc += tmp; }
    }
    __syncthreads();
    if (t < 256) {
        int excl = v + wtot[wid] - s;
        cur[2 * t] = excl;
        cur[2 * t + 1] = excl + a0;
    }
    __syncthreads();
    if (t < BW) {
        int g = b * BW + t;
        if (g < N_NODES) rowptr[g] = base + cur[t];
    }
    if (b == NBUCK - 1 && t == 0) rowptr[N_NODES] = bbase[NBUCK];
    __syncthreads();
    for (int i = t; i < cnt; i += 1024) {
        u32 code = mybuf[i];
        int pos = atomicAdd(&cur[(int)(code >> 17)], 1);
        lds_s[pos] = (int)(code & 0x1FFFFu);
    }
    __syncthreads();
    for (int i = t; i < cnt; i += 1024) ssrc[base + i] = lds_s[i];
}

// ---------------------------------------------------------------------------
// GEMM1: h[N,64](bf16) = x[N,128] @ W[128,64]; as_/ad_ score dots.
// ---------------------------------------------------------------------------
__global__ __launch_bounds__(256) void gemm1_kernel(
    const float* __restrict__ x, const float* __restrict__ W,
    const void* __restrict__ a_src, const void* __restrict__ a_dst,
    const int* __restrict__ flags,
    u16* __restrict__ h, float* __restrict__ as_, float* __restrict__ ad_)
{
    __shared__ float xs[256 * 33];   // 33.8 KB
    __shared__ float Wl[32 * 64];    // 8 KB
    const int t = threadIdx.x;
    const int node0 = blockIdx.x * 256;
    const int bf = flags[0];
    const int ng = t >> 3;
    const int cg = t & 7;

    float acc[8][8];
    #pragma unroll
    for (int i = 0; i < 8; ++i)
        #pragma unroll
        for (int j = 0; j < 8; ++j) acc[i][j] = 0.f;

    for (int kc = 0; kc < 4; ++kc) {
        const int kb = kc * 32;
        const int c4 = t & 7;
        #pragma unroll
        for (int p = 0; p < 8; ++p) {
            int row = (t >> 3) + p * 32;
            int n = node0 + row;
            float4 vv = make_float4(0.f, 0.f, 0.f, 0.f);
            if (n < N_NODES) {
                if (!bf) {
                    vv = *(const float4*)(x + (size_t)n * 128 + kb + c4 * 4);
                } else {
                    const u16* xh = (const u16*)x;
                    vv.x = bf2f(xh[(size_t)n * 128 + kb + c4 * 4 + 0]);
                    vv.y = bf2f(xh[(size_t)n * 128 + kb + c4 * 4 + 1]);
                    vv.z = bf2f(xh[(size_t)n * 128 + kb + c4 * 4 + 2]);
                    vv.w = bf2f(xh[(size_t)n * 128 + kb + c4 * 4 + 3]);
                }
            }
            float* dstp = &xs[row * 33 + c4 * 4];
            dstp[0] = vv.x; dstp[1] = vv.y; dstp[2] = vv.z; dstp[3] = vv.w;
        }
        if (!bf) {
            #pragma unroll
            for (int qq = 0; qq < 2; ++qq) {
                int f4 = t * 2 + qq;
                ((float4*)Wl)[f4] = ((const float4*)(W + (size_t)kb * 64))[f4];
            }
        } else {
            const u16* Wh = (const u16*)W;
            for (int i = t; i < 2048; i += 256) Wl[i] = bf2f(Wh[(size_t)kb * 64 + i]);
        }
        __syncthreads();

        for (int kk = 0; kk < 32; ++kk) {
            float xr[8];
            #pragma unroll
            for (int i = 0; i < 8; ++i) xr[i] = xs[(ng * 8 + i) * 33 + kk];
            float4 w0 = *(const float4*)&Wl[kk * 64 + cg * 8];
            float4 w1 = *(const float4*)&Wl[kk * 64 + cg * 8 + 4];
            const float wr[8] = {w0.x, w0.y, w0.z, w0.w, w1.x, w1.y, w1.z, w1.w};
            #pragma unroll
            for (int i = 0; i < 8; ++i)
                #pragma unroll
                for (int j = 0; j < 8; ++j)
                    acc[i][j] = fmaf(xr[i], wr[j], acc[i][j]);
        }
        __syncthreads();
    }

    float av[8], dv[8];
    #pragma unroll
    for (int j = 0; j < 8; ++j) {
        av[j] = ldf(a_src, cg * 8 + j, bf);
        dv[j] = ldf(a_dst, cg * 8 + j, bf);
    }
    #pragma unroll
    for (int i = 0; i < 8; ++i) {
        int n = node0 + ng * 8 + i;
        float ps = 0.f, pd = 0.f;
        #pragma unroll
        for (int j = 0; j < 8; ++j) { ps += acc[i][j] * av[j]; pd += acc[i][j] * dv[j]; }
        #pragma unroll
        for (int off = 1; off < 8; off <<= 1) {
            ps += __shfl_xor(ps, off);
            pd += __shfl_xor(pd, off);
        }
        if (n < N_NODES) {
            uint4 hv;
            hv.x = (u32)f2bf(acc[i][0]) | ((u32)f2bf(acc[i][1]) << 16);
            hv.y = (u32)f2bf(acc[i][2]) | ((u32)f2bf(acc[i][3]) << 16);
            hv.z = (u32)f2bf(acc[i][4]) | ((u32)f2bf(acc[i][5]) << 16);
            hv.w = (u32)f2bf(acc[i][6]) | ((u32)f2bf(acc[i][7]) << 16);
            *(uint4*)&h[(size_t)n * 64 + cg * 8] = hv;
            if (cg == 0) { as_[n] = ps; ad_[n] = pd; }
        }
    }
}

// ---------------------------------------------------------------------------
// Layer-1 aggregation, C=64. One wave per dst. Half-split u32 gather with
// wave-private LDS pair table (r1: replaced readlane+cndmask VALU chain).
// ---------------------------------------------------------------------------
__global__ __launch_bounds__(256) void gat_agg64_kernel(
    const int* __restrict__ rowptr, const int* __restrict__ ssrc,
    const float* __restrict__ as_, const float* __restrict__ ad_,
    const u16* __restrict__ h, float* __restrict__ agg)
{
    __shared__ uint2 pr[4][64];      // per-wave {ex_bits, sj<<7} pair table
    const int lane = threadIdx.x & 63;
    const int wid = threadIdx.x >> 6;
    const int dst = blockIdx.x * 4 + wid;
    if (dst >= N_NODES) return;
    uint2* pairs = pr[wid];
    const int beg = rowptr[dst], end = rowptr[dst + 1];
    const float add = ad_[dst];
    const int half = lane >> 5;
    const int hw = lane & 31;                     // u32 index within 128-B row
    const char* __restrict__ hb = (const char*)h; // byte base of h
    const u32 boff = (u32)(hw * 4);

    float m = -1e30f, l = 0.f, acc0 = 0.f, acc1 = 0.f;
    for (int base = beg; base < end; base += 64) {
        int j = base + lane;
        int sj = 0;
        float sc = -1e30f;
        if (j < end) { sj = ssrc[j]; sc = lrelu(as_[sj] + add); }
        float cm = sc;
        #pragma unroll
        for (int off = 32; off > 0; off >>= 1) cm = fmaxf(cm, __shfl_xor(cm, off));
        float nm = fmaxf(m, cm);
        float scale = __expf(m - nm);
        float ex = (j < end) ? __expf(sc - nm) : 0.f;
        float cs = ex;
        #pragma unroll
        for (int off = 32; off > 0; off >>= 1) cs += __shfl_xor(cs, off);
        l = l * scale + cs;
        acc0 *= scale; acc1 *= scale;
        m = nm;

        // publish {weight, row byte-offset} for this 64-edge block
        pairs[lane] = make_uint2(__float_as_uint(ex), ((u32)sj) << 7);
        __builtin_amdgcn_wave_barrier();
        asm volatile("s_waitcnt lgkmcnt(0)" ::: "memory");

        const int cnt = min(64, end - base);
        int jj = 0;
        for (; jj + 8 <= cnt; jj += 8) {
            #pragma unroll
            for (int k = 0; k < 8; k += 2) {
                uint2 p = pairs[jj + k + half];
                float w = __uint_as_float(p.x);
                u32 qv = *(const u32*)(hb + (size_t)(p.y + boff));
                acc0 = fmaf(w, __uint_as_float(qv << 16), acc0);
                acc1 = fmaf(w, __uint_as_float(qv & 0xFFFF0000u), acc1);
            }
        }
        for (; jj + 2 <= cnt; jj += 2) {
            uint2 p = pairs[jj + half];
            float w = __uint_as_float(p.x);
            u32 qv = *(const u32*)(hb + (size_t)(p.y + boff));
            acc0 = fmaf(w, __uint_as_float(qv << 16), acc0);
            acc1 = fmaf(w, __uint_as_float(qv & 0xFFFF0000u), acc1);
        }
        if (jj < cnt) {   // odd leftover: only half==0 contributes
            uint2 p = pairs[jj];
            float w = half ? 0.f : __uint_as_float(p.x);
            u32 qv = *(const u32*)(hb + (size_t)(p.y + boff));
            acc0 = fmaf(w, __uint_as_float(qv << 16), acc0);
            acc1 = fmaf(w, __uint_as_float(qv & 0xFFFF0000u), acc1);
        }
        __builtin_amdgcn_wave_barrier();   // keep reads before next block's write
    }
    acc0 += __shfl_xor(acc0, 32);
    acc1 += __shfl_xor(acc1, 32);
    if (lane < 32) {
        float inv = 1.f / l;
        *(float2*)&agg[(size_t)dst * 64 + 2 * hw] = make_float2(acc0 * inv, acc1 * inv);
    }
}

// ---------------------------------------------------------------------------
// Layer-2 aggregation, C=32, quarter-split u32 gather with LDS pair-table
// broadcast; fused bias + log_softmax. Masked tail retires up to 3 edges.
// ---------------------------------------------------------------------------
__global__ __launch_bounds__(256) void gat_agg32_lsm_kernel(
    const int* __restrict__ rowptr, const int* __restrict__ ssrc,
    const float* __restrict__ as_, const float* __restrict__ ad_,
    const u16* __restrict__ h, const void* __restrict__ b2,
    const int* __restrict__ flags, float* __restrict__ out)
{
    __shared__ uint2 pr[4][64];      // per-wave {ex_bits, sj<<6} pair table
    const int lane = threadIdx.x & 63;
    const int wid = threadIdx.x >> 6;
    const int dst = blockIdx.x * 4 + wid;
    if (dst >= N_NODES) return;
    uint2* pairs = pr[wid];
    const int beg = rowptr[dst], end = rowptr[dst + 1];
    const float add = ad_[dst];
    const int q = lane >> 4;          // quarter 0..3 (edge within group of 4)
    const int i16 = lane & 15;        // u32 index within 64-B row
    const int bf = flags[0];
    const char* __restrict__ hb = (const char*)h;
    const u32 boff = (u32)(i16 * 4);

    float m = -1e30f, l = 0.f, acc0 = 0.f, acc1 = 0.f;
    for (int base = beg; base < end; base += 64) {
        int j = base + lane;
        int sj = 0;
        float sc = -1e30f;
        if (j < end) { sj = ssrc[j]; sc = lrelu(as_[sj] + add); }
        float cm = sc;
        #pragma unroll
        for (int off = 32; off > 0; off >>= 1) cm = fmaxf(cm, __shfl_xor(cm, off));
        float nm = fmaxf(m, cm);
        float scale = __expf(m - nm);
        float ex = (j < end) ? __expf(sc - nm) : 0.f;
        float cs = ex;
        #pragma unroll
        for (int off = 32; off > 0; off >>= 1) cs += __shfl_xor(cs, off);
        l = l * scale + cs;
        acc0 *= scale; acc1 *= scale;
        m = nm;

        pairs[lane] = make_uint2(__float_as_uint(ex), ((u32)sj) << 6);
        __builtin_amdgcn_wave_barrier();
        asm volatile("s_waitcnt lgkmcnt(0)" ::: "memory");

        const int cnt = min(64, end - base);
        int jj = 0;
        for (; jj + 8 <= cnt; jj += 8) {
            #pragma unroll
            for (int k = 0; k < 8; k += 4) {
                uint2 p = pairs[jj + k + q];
                float w = __uint_as_float(p.x);
                u32 qv = *(const u32*)(hb + (size_t)(p.y + boff));
                acc0 = fmaf(w, __uint_as_float(qv << 16), acc0);
                acc1 = fmaf(w, __uint_as_float(qv & 0xFFFF0000u), acc1);
            }
        }
        for (; jj + 4 <= cnt; jj += 4) {
            uint2 p = pairs[jj + q];
            float w = __uint_as_float(p.x);
            u32 qv = *(const u32*)(hb + (size_t)(p.y + boff));
            acc0 = fmaf(w, __uint_as_float(qv << 16), acc0);
            acc1 = fmaf(w, __uint_as_float(qv & 0xFFFF0000u), acc1);
        }
        {   // masked tail: up to 3 leftover edges in one pass (quarter q takes jj+q)
            int rem = cnt - jj;
            if (rem > 0) {
                uint2 p = pairs[jj + min(q, rem - 1)];
                float w = (q < rem) ? __uint_as_float(p.x) : 0.f;
                u32 qv = *(const u32*)(hb + (size_t)(p.y + boff));
                acc0 = fmaf(w, __uint_as_float(qv << 16), acc0);
                acc1 = fmaf(w, __uint_as_float(qv & 0xFFFF0000u), acc1);
            }
        }
        __builtin_amdgcn_wave_barrier();   // keep reads before next block's write
    }
    acc0 += __shfl_xor(acc0, 16); acc0 += __shfl_xor(acc0, 32);
    acc1 += __shfl_xor(acc1, 16); acc1 += __shfl_xor(acc1, 32);

    // fused bias + log_softmax: 16 lanes x 2 channels (replicated across quarters)
    float inv = 1.f / l;
    float v0 = acc0 * inv + ldf(b2, 2 * i16, bf);
    float v1 = acc1 * inv + ldf(b2, 2 * i16 + 1, bf);
    float mx = fmaxf(v0, v1);
    #pragma unroll
    for (int off = 1; off < 16; off <<= 1) mx = fmaxf(mx, __shfl_xor(mx, off));
    float ss = __expf(v0 - mx) + __expf(v1 - mx);
    #pragma unroll
    for (int off = 1; off < 16; off <<= 1) ss += __shfl_xor(ss, off);
    float lg = mx + __logf(ss);
    if (lane < 16)
        *(float2*)&out[(size_t)dst * 32 + 2 * i16] = make_float2(v0 - lg, v1 - lg);
}

// ---------------------------------------------------------------------------
// GEMM2 (r2 rewrite): hin = relu(agg1 + b1); h2[N,32](bf16) = hin @ W[64,32].
// 128-node tile, 256 threads, 4 nodes x 4 channels per thread.
// float4-coalesced staging (old version used scalar loads + 204 VGPR ->
// 9% occupancy -> 64 us for an 819-MFLOP GEMM). VALU floor ~10 us.
// ---------------------------------------------------------------------------
#define G2_TILE 128

__global__ __launch_bounds__(256, 3) void gemm2_kernel(
    const float* __restrict__ agg1, const void* __restrict__ b1,
    const u32* __restrict__ W32, const void* __restrict__ a_src,
    const void* __restrict__ a_dst, const int* __restrict__ flags,
    u16* __restrict__ h, float* __restrict__ as_, float* __restrict__ ad_)
{
    __shared__ __align__(16) float Wl[64 * 32];        // 8 KB
    __shared__ __align__(16) float xs[G2_TILE * 68];   // 34.8 KB (pad 68: 16B-aligned rows)
    const int tid = threadIdx.x;
    const int node0 = blockIdx.x * G2_TILE;
    const int bf = flags[0];

    // stage W2 as f32
    if (bf) {
        for (int i = tid; i < 1024; i += 256) {
            u32 u = W32[i];
            *(float2*)&Wl[2 * i] = make_float2(__uint_as_float(u << 16),
                                               __uint_as_float(u & 0xFFFF0000u));
        }
    } else {
        for (int i = tid; i < 2048; i += 256) Wl[i] = __uint_as_float(W32[i]);
    }
    // stage hin = relu(agg1 + b1), float4-coalesced (2048 float4s per block)
    #pragma unroll
    for (int it = 0; it < 8; ++it) {
        int i = tid + it * 256;           // [0, 2048)
        int nl = i >> 4;                  // local node 0..127
        int k  = (i & 15) * 4;
        int n = node0 + nl;
        float4 v = make_float4(0.f, 0.f, 0.f, 0.f);
        if (n < N_NODES) v = *(const float4*)(agg1 + (size_t)n * 64 + k);
        v.x = fmaxf(v.x + ldf(b1, k + 0, bf), 0.f);
        v.y = fmaxf(v.y + ldf(b1, k + 1, bf), 0.f);
        v.z = fmaxf(v.z + ldf(b1, k + 2, bf), 0.f);
        v.w = fmaxf(v.w + ldf(b1, k + 3, bf), 0.f);
        *(float4*)&xs[nl * 68 + k] = v;
    }
    __syncthreads();

    const int ch0 = (tid & 7) * 4;        // 4 output channels
    const int nb0 = (tid >> 3) * 4;       // 4 local nodes
    float acc[4][4];
    #pragma unroll
    for (int j = 0; j < 4; ++j)
        #pragma unroll
        for (int c = 0; c < 4; ++c) acc[j][c] = 0.f;

    #pragma unroll 4
    for (int k0 = 0; k0 < 64; k0 += 4) {
        float4 xv0 = *(const float4*)&xs[(nb0 + 0) * 68 + k0];
        float4 xv1 = *(const float4*)&xs[(nb0 + 1) * 68 + k0];
        float4 xv2 = *(const float4*)&xs[(nb0 + 2) * 68 + k0];
        float4 xv3 = *(const float4*)&xs[(nb0 + 3) * 68 + k0];
        const float* xp[4] = { (const float*)&xv0, (const float*)&xv1,
                               (const float*)&xv2, (const float*)&xv3 };
        #pragma unroll
        for (int kk = 0; kk < 4; ++kk) {
            float4 w = *(const float4*)&Wl[(k0 + kk) * 32 + ch0];
            #pragma unroll
            for (int j = 0; j < 4; ++j) {
                float xvv = xp[j][kk];
                acc[j][0] = fmaf(xvv, w.x, acc[j][0]);
                acc[j][1] = fmaf(xvv, w.y, acc[j][1]);
                acc[j][2] = fmaf(xvv, w.z, acc[j][2]);
                acc[j][3] = fmaf(xvv, w.w, acc[j][3]);
            }
        }
    }

    float av[4], dv[4];
    #pragma unroll
    for (int c = 0; c < 4; ++c) {
        av[c] = ldf(a_src, ch0 + c, bf);
        dv[c] = ldf(a_dst, ch0 + c, bf);
    }
    #pragma unroll
    for (int j = 0; j < 4; ++j) {
        float ps = acc[j][0] * av[0] + acc[j][1] * av[1]
                 + acc[j][2] * av[2] + acc[j][3] * av[3];
        float pd = acc[j][0] * dv[0] + acc[j][1] * dv[1]
                 + acc[j][2] * dv[2] + acc[j][3] * dv[3];
        #pragma unroll
        for (int off = 1; off < 8; off <<= 1) {
            ps += __shfl_xor(ps, off);
            pd += __shfl_xor(pd, off);
        }
        int n = node0 + nb0 + j;
        if (n < N_NODES) {
            u32 p0 = (u32)f2bf(acc[j][0]) | ((u32)f2bf(acc[j][1]) << 16);
            u32 p1 = (u32)f2bf(acc[j][2]) | ((u32)f2bf(acc[j][3]) << 16);
            *(uint2*)&h[(size_t)n * 32 + ch0] = make_uint2(p0, p1);
            if ((tid & 7) == 0) { as_[n] = ps; ad_[n] = pd; }
        }
    }
}

// ---------------------------------------------------------------------------
extern "C" void kernel_launch(void* const* d_in, const int* in_sizes, int n_in,
                              void* d_out, int out_size, void* d_ws, size_t ws_size,
                              hipStream_t stream) {
    const float* x   = (const float*)d_in[0];
    const int* ei    = (const int*)d_in[1];
    const float* W1  = (const float*)d_in[2];
    const void* a_s1 = d_in[3];
    const void* a_d1 = d_in[4];
    const void* b1   = d_in[5];
    const u32* W2    = (const u32*)d_in[6];
    const void* a_s2 = d_in[7];
    const void* a_d2 = d_in[8];
    const void* b2   = d_in[9];
    float* out = (float*)d_out;

    // workspace carve-up (~55 MB)
    char* base = (char*)d_ws;
    int* flags = (int*)base;
    u16* h     = (u16*)(base + 64);                           // N*64 bf16 (reused N*32)
    char* q = base + 64 + (size_t)N_NODES * 64 * 2;
    float* as1 = (float*)q; q += (size_t)N_NODES * 4;
    float* ad1 = (float*)q; q += (size_t)N_NODES * 4;
    float* as2 = (float*)q; q += (size_t)N_NODES * 4;
    float* ad2 = (float*)q; q += (size_t)N_NODES * 4;
    float* agg1 = (float*)q; q += (size_t)N_NODES * 64 * 4;
    u32*  bbuf  = (u32*)q;  q += (size_t)NBUCK * BCAP * 4;    // 8.03 MB
    int* rowptr = (int*)q;  q += (size_t)(N_NODES + 16) * 4;
    int* ssrc   = (int*)q;  q += (size_t)ET * 4;
    int* bcnt   = (int*)q;  q += 256 * 4;
    int* bbase  = (int*)q;  q += 256 * 4;

    detect_kernel<<<1, 64, 0, stream>>>((const u32*)x, ei, flags, bcnt);

    // CSR by dst via 2-pass bucket sort (rowptr built in scatter)
    bin_kernel<<<(ET + BINCH - 1) / BINCH, 256, 0, stream>>>(ei, flags, bcnt, bbuf);
    bscan_kernel<<<1, 256, 0, stream>>>(bcnt, bbase);
    scatter_kernel<<<NBUCK, 1024, 0, stream>>>(bcnt, bbase, bbuf, rowptr, ssrc);

    // layer 1
    gemm1_kernel<<<(N_NODES + 255) / 256, 256, 0, stream>>>(x, W1, a_s1, a_d1, flags, h, as1, ad1);
    gat_agg64_kernel<<<(N_NODES + 3) / 4, 256, 0, stream>>>(rowptr, ssrc, as1, ad1, h, agg1);

    // layer 2 (lsm fused; writes d_out directly)
    gemm2_kernel<<<(N_NODES + G2_TILE - 1) / G2_TILE, 256, 0, stream>>>(agg1, b1, W2, a_s2, a_d2, flags, h, as2, ad2);
    gat_agg32_lsm_kernel<<<(N_NODES + 3) / 4, 256, 0, stream>>>(rowptr, ssrc, as2, ad2, h, b2, flags, out);
}